// Round 1
// baseline (131.825 us; speedup 1.0000x reference)
//
#include <hip/hip_runtime.h>
#include <hip/hip_bf16.h>

// Problem constants: B=8, Te=512, Td=128, D_ENC=D_DEC=512, ATT=256
// Workspace layout: Whl [4096,256] f32 (pre-scaled by 2*log2e), Ul [1024,256] f32 (pre-scaled)

// ---------------------------------------------------------------------------
// Kernel 1: two fp32 GEMMs in one launch.
//   blocks 0..255 : Whl = (values[4096,512] @ W_h[512,256]) * 2log2e
//   blocks 256..319: Ul  = (query [1024,512] @ U_a[512,256]) * 2log2e
// 64x64 output tile per block, BK=16, 256 threads, 4x4 microtile/thread.
// ---------------------------------------------------------------------------
__global__ __launch_bounds__(256) void gemm_pre(
    const float* __restrict__ values, const float* __restrict__ query,
    const float* __restrict__ W_h, const float* __restrict__ U_a,
    float* __restrict__ WhO, float* __restrict__ UO)
{
    __shared__ float As[16][68];  // As[k][m], padded
    __shared__ float Bs[16][68];  // Bs[k][n], padded (68: keeps float4 align + low conflicts)

    int bid = blockIdx.x;
    const float* A; const float* W; float* C;
    int mt, nt;
    if (bid < 256) { A = values; W = W_h; C = WhO; mt = bid >> 2; nt = bid & 3; }
    else { int b2 = bid - 256; A = query; W = U_a; C = UO; mt = b2 >> 2; nt = b2 & 3; }
    const int m0 = mt * 64, n0 = nt * 64;
    const int tid = threadIdx.x;
    const int tx = tid & 15, ty = tid >> 4;

    const int ar = tid >> 2;           // 0..63 : A row within tile
    const int ak = (tid & 3) * 4;      // 0,4,8,12 : k quad
    const int wk = tid >> 4;           // 0..15 : W k row
    const int wn = (tid & 15) * 4;     // 0..60 : W n quad

    float acc[4][4] = {};

    for (int k0 = 0; k0 < 512; k0 += 16) {
        __syncthreads();
        float4 av = *(const float4*)&A[(size_t)(m0 + ar) * 512 + k0 + ak];
        As[ak + 0][ar] = av.x;
        As[ak + 1][ar] = av.y;
        As[ak + 2][ar] = av.z;
        As[ak + 3][ar] = av.w;
        float4 wv = *(const float4*)&W[(size_t)(k0 + wk) * 256 + n0 + wn];
        *(float4*)&Bs[wk][wn] = wv;
        __syncthreads();
        #pragma unroll
        for (int k = 0; k < 16; ++k) {
            float4 a4 = *(const float4*)&As[k][ty * 4];
            float4 b4 = *(const float4*)&Bs[k][tx * 4];
            float a_[4] = {a4.x, a4.y, a4.z, a4.w};
            float b_[4] = {b4.x, b4.y, b4.z, b4.w};
            #pragma unroll
            for (int i = 0; i < 4; ++i)
                #pragma unroll
                for (int j = 0; j < 4; ++j)
                    acc[i][j] = fmaf(a_[i], b_[j], acc[i][j]);
        }
    }

    const float SCL = 2.8853900817779268f;  // 2*log2(e): folds tanh's e^{2x} into exp2
    #pragma unroll
    for (int i = 0; i < 4; ++i) {
        float4 o = {acc[i][0] * SCL, acc[i][1] * SCL, acc[i][2] * SCL, acc[i][3] * SCL};
        *(float4*)&C[(size_t)(m0 + ty * 4 + i) * 256 + n0 + tx * 4] = o;
    }
}

// ---------------------------------------------------------------------------
// Kernel 2: fused scores + softmax + context.
// Grid: 256 blocks = 8 b x 32 t-groups (4 t each). 512 threads (8 waves).
// Thread (t = tid>>7, sl = tid&127) computes score dots for s = sl + 128*tile.
// ---------------------------------------------------------------------------
__global__ __launch_bounds__(512) void attn_fused(
    const float* __restrict__ Whl, const float* __restrict__ Ul,
    const float* __restrict__ Va, const float* __restrict__ values,
    float* __restrict__ out_c, float* __restrict__ out_e)
{
    __shared__ float WhT[128][257];  // +1 pad: bank=(s+a)%32 -> conflict-free b32 reads
    __shared__ float Us[4][256];     // wave-uniform broadcast reads
    __shared__ float Vs[256];
    __shared__ float Ps[4][512];
    __shared__ float red[16];

    const int tid = threadIdx.x;
    const int b = blockIdx.x >> 5;
    const int t0 = (blockIdx.x & 31) * 4;

    // load scaled U rows and V
    for (int i = tid; i < 4 * 256; i += 512)
        Us[i >> 8][i & 255] = Ul[(size_t)(b * 128 + t0 + (i >> 8)) * 256 + (i & 255)];
    if (tid < 256) Vs[tid] = Va[tid];

    const int t = tid >> 7;          // 0..3
    const int sl = tid & 127;        // 0..127
    const int srow = tid & 127;      // staging: one row per lane -> conflict-free LDS writes
    const int g = tid >> 7;          // staging chunk phase 0..3

    float sc[4];
    for (int tile = 0; tile < 4; ++tile) {
        __syncthreads();
        // stage Whl rows [b*512 + tile*128 + 0..127][0..255]
        const float* src = Whl + (size_t)(b * 512 + tile * 128 + srow) * 256;
        #pragma unroll
        for (int it = 0; it < 16; ++it) {
            int cf = (g + 4 * it) * 4;          // float offset, stride 16 floats
            float4 v = *(const float4*)&src[cf];
            WhT[srow][cf + 0] = v.x;            // bank=(srow+cf+j)%32: lanes differ in srow -> free
            WhT[srow][cf + 1] = v.y;
            WhT[srow][cf + 2] = v.z;
            WhT[srow][cf + 3] = v.w;
        }
        __syncthreads();
        float acc = 0.f;
        const float* wr = WhT[sl];
        const float* ur = Us[t];
        #pragma unroll 8
        for (int a = 0; a < 256; ++a) {
            // tanh(x) = 1 - 2/(1+e^{2x}); inputs pre-scaled by 2*log2e -> e^{2x} = exp2(wr+ur)
            float x = wr[a] + ur[a];
            float e = __builtin_amdgcn_exp2f(x);
            float th = fmaf(-2.f, __builtin_amdgcn_rcpf(1.f + e), 1.f);
            acc = fmaf(Vs[a], th, acc);
        }
        sc[tile] = acc;
    }

    // softmax over 512 s per t (2 waves per t)
    float mx = fmaxf(fmaxf(sc[0], sc[1]), fmaxf(sc[2], sc[3]));
    #pragma unroll
    for (int off = 32; off > 0; off >>= 1)
        mx = fmaxf(mx, __shfl_xor(mx, off));
    const int wave = tid >> 6;
    if ((tid & 63) == 0) red[wave] = mx;
    __syncthreads();
    mx = fmaxf(red[t * 2], red[t * 2 + 1]);

    float e4[4], ssum = 0.f;
    #pragma unroll
    for (int i = 0; i < 4; ++i) {
        e4[i] = __builtin_amdgcn_exp2f((sc[i] - mx) * 1.4426950408889634f);
        ssum += e4[i];
    }
    #pragma unroll
    for (int off = 32; off > 0; off >>= 1)
        ssum += __shfl_xor(ssum, off);
    if ((tid & 63) == 0) red[8 + wave] = ssum;
    __syncthreads();
    const float inv = 1.0f / (red[8 + t * 2] + red[8 + t * 2 + 1]);

    float* erow = out_e + (size_t)(b * 128 + t0 + t) * 512;
    #pragma unroll
    for (int i = 0; i < 4; ++i) {
        float p = e4[i] * inv;
        Ps[t][sl + 128 * i] = p;
        erow[sl + 128 * i] = p;
    }
    __syncthreads();

    // context: c[t][e] = sum_s p[s] * values[b][s][e]; float4 per thread over e
    const float* vb = values + (size_t)b * 512 * 512;
    const float* pr = Ps[t];
    const int el = (tid & 127) * 4;
    float4 accv = {0.f, 0.f, 0.f, 0.f};
    #pragma unroll 4
    for (int s = 0; s < 512; ++s) {
        float p = pr[s];
        float4 v4 = *(const float4*)&vb[(size_t)s * 512 + el];
        accv.x = fmaf(p, v4.x, accv.x);
        accv.y = fmaf(p, v4.y, accv.y);
        accv.z = fmaf(p, v4.z, accv.z);
        accv.w = fmaf(p, v4.w, accv.w);
    }
    *(float4*)&out_c[(size_t)(b * 128 + t0 + t) * 512 + el] = accv;
}

// ---------------------------------------------------------------------------
extern "C" void kernel_launch(void* const* d_in, const int* in_sizes, int n_in,
                              void* d_out, int out_size, void* d_ws, size_t ws_size,
                              hipStream_t stream) {
    const float* values = (const float*)d_in[0];  // [8,512,512]
    const float* query  = (const float*)d_in[1];  // [8,128,512]
    const float* W_h    = (const float*)d_in[2];  // [512,256]
    const float* U_a    = (const float*)d_in[3];  // [512,256]
    const float* V_a    = (const float*)d_in[4];  // [1,256]

    float* ws  = (float*)d_ws;
    float* Whl = ws;                   // 4096*256 f32 = 4 MB
    float* Ul  = ws + 4096 * 256;      // 1024*256 f32 = 1 MB

    float* out_c = (float*)d_out;                  // [8,128,512]
    float* out_e = out_c + 8 * 128 * 512;          // [8,128,512]

    hipLaunchKernelGGL(gemm_pre, dim3(320), dim3(256), 0, stream,
                       values, query, W_h, U_a, Whl, Ul);
    hipLaunchKernelGGL(attn_fused, dim3(256), dim3(512), 0, stream,
                       Whl, Ul, V_a, values, out_c, out_e);
}

// Round 2
// 83.815 us; speedup vs baseline: 1.5728x; 1.5728x over previous
//
#include <hip/hip_runtime.h>
#include <hip/hip_bf16.h>

// B=8, Te=512, Td=128, D_ENC=D_DEC=512, ATT=256
// ws: Whl [4096,256] f32 (scaled by 2*log2e), Ul [1024,256] f32 (scaled), scores [8,128,512] f32

// ---------------------------------------------------------------------------
// Kernel 1: two fp32 GEMMs. blocks 0..255: Whl = values@W_h * SCL
//                           blocks 256..319: Ul = query@U_a * SCL
// 64x64 tile, BK=16, 256 thr, 4x4 micro, register-prefetch double buffer.
// ---------------------------------------------------------------------------
__global__ __launch_bounds__(256) void gemm_pre(
    const float* __restrict__ values, const float* __restrict__ query,
    const float* __restrict__ W_h, const float* __restrict__ U_a,
    float* __restrict__ WhO, float* __restrict__ UO)
{
    __shared__ float As[16][68];
    __shared__ float Bs[16][68];

    int bid = blockIdx.x;
    const float* A; const float* W; float* C;
    int mt, nt;
    if (bid < 256) { A = values; W = W_h; C = WhO; mt = bid >> 2; nt = bid & 3; }
    else { int b2 = bid - 256; A = query; W = U_a; C = UO; mt = b2 >> 2; nt = b2 & 3; }
    const int m0 = mt * 64, n0 = nt * 64;
    const int tid = threadIdx.x;
    const int tx = tid & 15, ty = tid >> 4;

    const int ar = tid >> 2;
    const int ak = (tid & 3) * 4;
    const int wk = tid >> 4;
    const int wn = (tid & 15) * 4;

    float acc[4][4] = {};

    float4 av = *(const float4*)&A[(size_t)(m0 + ar) * 512 + ak];
    float4 wv = *(const float4*)&W[(size_t)wk * 256 + n0 + wn];

    for (int k0 = 0; k0 < 512; k0 += 16) {
        __syncthreads();
        As[ak + 0][ar] = av.x;
        As[ak + 1][ar] = av.y;
        As[ak + 2][ar] = av.z;
        As[ak + 3][ar] = av.w;
        *(float4*)&Bs[wk][wn] = wv;
        __syncthreads();
        if (k0 + 16 < 512) {
            av = *(const float4*)&A[(size_t)(m0 + ar) * 512 + k0 + 16 + ak];
            wv = *(const float4*)&W[(size_t)(k0 + 16 + wk) * 256 + n0 + wn];
        }
        #pragma unroll
        for (int k = 0; k < 16; ++k) {
            float4 a4 = *(const float4*)&As[k][ty * 4];
            float4 b4 = *(const float4*)&Bs[k][tx * 4];
            float a_[4] = {a4.x, a4.y, a4.z, a4.w};
            float b_[4] = {b4.x, b4.y, b4.z, b4.w};
            #pragma unroll
            for (int i = 0; i < 4; ++i)
                #pragma unroll
                for (int j = 0; j < 4; ++j)
                    acc[i][j] = fmaf(a_[i], b_[j], acc[i][j]);
        }
    }

    const float SCL = 2.8853900817779268f;  // 2*log2(e)
    #pragma unroll
    for (int i = 0; i < 4; ++i) {
        float4 o = {acc[i][0] * SCL, acc[i][1] * SCL, acc[i][2] * SCL, acc[i][3] * SCL};
        *(float4*)&C[(size_t)(m0 + ty * 4 + i) * 256 + n0 + tx * 4] = o;
    }
}

// ---------------------------------------------------------------------------
// Kernel 2: scores. One thread per (t,s). Grid 2048 = 8b x 8 t-tiles x 32 s-tiles.
// Block 256 thr: t = tid>>4 (16 t's), s = tid&15 (16 s's). a chunked by 128.
// b = bid&7 -> blocks of one b land on one XCD (round-robin dispatch) -> L2-resident.
// ---------------------------------------------------------------------------
__global__ __launch_bounds__(256) void scores_k(
    const float* __restrict__ Whl, const float* __restrict__ Ul,
    const float* __restrict__ Va, float* __restrict__ scores)
{
    __shared__ float Ws[16][132];  // +4 pad: bank=(s*4+a)%32, 4-row groups distinct
    __shared__ float Us[16][132];
    __shared__ float Vs[256];

    const int bid = blockIdx.x;
    const int b = bid & 7;
    const int rem = bid >> 3;            // 0..255
    const int t0 = (rem >> 5) * 16;      // 8 t-tiles
    const int s0 = (rem & 31) * 16;      // 32 s-tiles
    const int tid = threadIdx.x;

    Vs[tid] = Va[tid];

    const int r = tid >> 4;              // staging row 0..15
    const int c4 = (tid & 15) * 4;       // staging col quad
    const int t = tid >> 4;              // compute: t index
    const int s = tid & 15;              // compute: s index (consecutive lanes -> coalesced store)

    const float* wsrc = Whl + (size_t)(b * 512 + s0 + r) * 256;
    const float* usrc = Ul + (size_t)(b * 128 + t0 + r) * 256;

    float acc = 0.f;
    for (int c0 = 0; c0 < 256; c0 += 128) {
        __syncthreads();
        *(float4*)&Ws[r][c4]      = *(const float4*)&wsrc[c0 + c4];
        *(float4*)&Ws[r][64 + c4] = *(const float4*)&wsrc[c0 + 64 + c4];
        *(float4*)&Us[r][c4]      = *(const float4*)&usrc[c0 + c4];
        *(float4*)&Us[r][64 + c4] = *(const float4*)&usrc[c0 + 64 + c4];
        __syncthreads();
        const float* wr = Ws[s];
        const float* ur = Us[t];
        #pragma unroll 2
        for (int a = 0; a < 128; a += 4) {
            float4 w = *(const float4*)&wr[a];
            float4 u = *(const float4*)&ur[a];
            float4 vv = *(const float4*)&Vs[c0 + a];
            float x0 = w.x + u.x, x1 = w.y + u.y, x2 = w.z + u.z, x3 = w.w + u.w;
            float e0 = __builtin_amdgcn_exp2f(x0);
            float e1 = __builtin_amdgcn_exp2f(x1);
            float e2 = __builtin_amdgcn_exp2f(x2);
            float e3 = __builtin_amdgcn_exp2f(x3);
            float r0 = __builtin_amdgcn_rcpf(1.0f + e0);
            float r1 = __builtin_amdgcn_rcpf(1.0f + e1);
            float r2 = __builtin_amdgcn_rcpf(1.0f + e2);
            float r3 = __builtin_amdgcn_rcpf(1.0f + e3);
            acc = fmaf(vv.x, fmaf(-2.f, r0, 1.f), acc);
            acc = fmaf(vv.y, fmaf(-2.f, r1, 1.f), acc);
            acc = fmaf(vv.z, fmaf(-2.f, r2, 1.f), acc);
            acc = fmaf(vv.w, fmaf(-2.f, r3, 1.f), acc);
        }
    }
    scores[(size_t)(b * 128 + t0 + t) * 512 + s0 + s] = acc;
}

// ---------------------------------------------------------------------------
// Kernel 3: softmax (no max-sub: |score| <= sum|V| ~ 7, fp32-safe) + context.
// Grid 256 = 8b x 32 t-groups(4). 512 thr. b = bid&7 -> values[b] L2-resident/XCD.
// Context: thread (e-pair = (tid&255)*2, s-half = tid>>8), partial-reduce via LDS.
// ---------------------------------------------------------------------------
__global__ __launch_bounds__(512) void softmax_ctx(
    const float* __restrict__ scores, const float* __restrict__ values,
    float* __restrict__ out_c, float* __restrict__ out_e)
{
    __shared__ float Ps[4][512];
    __shared__ float Part[4][512];

    const int bid = blockIdx.x;
    const int b = bid & 7;
    const int t0 = (bid >> 3) * 4;
    const int tid = threadIdx.x;

    if (tid < 256) {
        const int row = tid >> 6, lane = tid & 63;
        const float* srow = scores + (size_t)(b * 128 + t0 + row) * 512;
        float e[8]; float ssum = 0.f;
        #pragma unroll
        for (int k = 0; k < 8; ++k) {
            float v = srow[k * 64 + lane];
            e[k] = __builtin_amdgcn_exp2f(v * 1.4426950408889634f);
            ssum += e[k];
        }
        #pragma unroll
        for (int off = 32; off > 0; off >>= 1)
            ssum += __shfl_xor(ssum, off);
        const float inv = 1.0f / ssum;
        float* erow = out_e + (size_t)(b * 128 + t0 + row) * 512;
        #pragma unroll
        for (int k = 0; k < 8; ++k) {
            float p = e[k] * inv;
            Ps[row][k * 64 + lane] = p;
            erow[k * 64 + lane] = p;
        }
    }
    __syncthreads();

    const int e2 = (tid & 255) * 2;
    const int sh = tid >> 8;                  // s-half 0/1
    const float* vb = values + (size_t)b * 262144 + (size_t)(sh * 256) * 512;
    const float* p0 = &Ps[0][sh * 256];
    const float* p1 = &Ps[1][sh * 256];
    const float* p2 = &Ps[2][sh * 256];
    const float* p3 = &Ps[3][sh * 256];
    float a0x = 0.f, a0y = 0.f, a1x = 0.f, a1y = 0.f;
    float a2x = 0.f, a2y = 0.f, a3x = 0.f, a3y = 0.f;
    #pragma unroll 8
    for (int s2 = 0; s2 < 256; ++s2) {
        float2 v2 = *(const float2*)&vb[(size_t)s2 * 512 + e2];
        float q0 = p0[s2], q1 = p1[s2], q2 = p2[s2], q3 = p3[s2];
        a0x = fmaf(q0, v2.x, a0x); a0y = fmaf(q0, v2.y, a0y);
        a1x = fmaf(q1, v2.x, a1x); a1y = fmaf(q1, v2.y, a1y);
        a2x = fmaf(q2, v2.x, a2x); a2y = fmaf(q2, v2.y, a2y);
        a3x = fmaf(q3, v2.x, a3x); a3y = fmaf(q3, v2.y, a3y);
    }
    if (sh) {
        *(float2*)&Part[0][e2] = {a0x, a0y};
        *(float2*)&Part[1][e2] = {a1x, a1y};
        *(float2*)&Part[2][e2] = {a2x, a2y};
        *(float2*)&Part[3][e2] = {a3x, a3y};
    }
    __syncthreads();
    if (!sh) {
        float2 o0 = {a0x + Part[0][e2], a0y + Part[0][e2 + 1]};
        float2 o1 = {a1x + Part[1][e2], a1y + Part[1][e2 + 1]};
        float2 o2 = {a2x + Part[2][e2], a2y + Part[2][e2 + 1]};
        float2 o3 = {a3x + Part[3][e2], a3y + Part[3][e2 + 1]};
        *(float2*)&out_c[(size_t)(b * 128 + t0 + 0) * 512 + e2] = o0;
        *(float2*)&out_c[(size_t)(b * 128 + t0 + 1) * 512 + e2] = o1;
        *(float2*)&out_c[(size_t)(b * 128 + t0 + 2) * 512 + e2] = o2;
        *(float2*)&out_c[(size_t)(b * 128 + t0 + 3) * 512 + e2] = o3;
    }
}

// ---------------------------------------------------------------------------
extern "C" void kernel_launch(void* const* d_in, const int* in_sizes, int n_in,
                              void* d_out, int out_size, void* d_ws, size_t ws_size,
                              hipStream_t stream) {
    const float* values = (const float*)d_in[0];  // [8,512,512]
    const float* query  = (const float*)d_in[1];  // [8,128,512]
    const float* W_h    = (const float*)d_in[2];  // [512,256]
    const float* U_a    = (const float*)d_in[3];  // [512,256]
    const float* V_a    = (const float*)d_in[4];  // [1,256]

    float* ws     = (float*)d_ws;
    float* Whl    = ws;                        // 4096*256
    float* Ul     = ws + 4096 * 256;           // 1024*256
    float* scores = Ul + 1024 * 256;           // 8*128*512

    float* out_c = (float*)d_out;              // [8,128,512]
    float* out_e = out_c + 8 * 128 * 512;      // [8,128,512]

    hipLaunchKernelGGL(gemm_pre, dim3(320), dim3(256), 0, stream,
                       values, query, W_h, U_a, Whl, Ul);
    hipLaunchKernelGGL(scores_k, dim3(2048), dim3(256), 0, stream,
                       Whl, Ul, V_a, scores);
    hipLaunchKernelGGL(softmax_ctx, dim3(256), dim3(512), 0, stream,
                       scores, values, out_c, out_e);
}